// Round 6
// baseline (268.301 us; speedup 1.0000x reference)
//
#include <hip/hip_runtime.h>
#include <hip/hip_bf16.h>
#include <hip/hip_fp16.h>

#define HD 64
#define NODE_DIM 5
#define NEG_SLOPE 0.2f
#define GT 64       // gemm node-tile per block
#define BSH 9       // bucket shift: 512 nodes/bucket
#define BNODES 512  // nodes per bucket
#define NBMAX 512   // static bucket array cap (N<=262144)
#define BCAP 4096   // fixed bucket window capacity (mean 3072, sigma 55 -> 18 sigma slack)
#define EPB 8       // edges per thread in bucket kernels
#define LDH 72      // LDS row stride in halves: 144B = 16B-aligned, bank-stride 4 -> only free 2-way aliasing

typedef _Float16 f16x8 __attribute__((ext_vector_type(8)));
typedef float f32x4 __attribute__((ext_vector_type(4)));

// R27: gemm1 || partition fused (Bresenham roles, union'd LDS, LDS bucket
// sort -> coalesced window runs). R28: gather2+pool+MLP fused per-graph
// (h_final never materialized: kills a 25.6MB write + 25.6MB read + 1 gap).

__global__ void zero_k(int* __restrict__ p, int total) {
    int i = blockIdx.x * blockDim.x + threadIdx.x;
    if (i < total) p[i] = 0;
}

union FusedSM {
    struct {
        _Float16 hs[GT * LDH];        // h tile  [node][k]
        _Float16 Wt[HD * LDH];        // W^T     [dim][k]
        float xe[GT * NODE_DIM];
        float we[NODE_DIM * HD + HD];
    } g;
    struct {
        int lcnt[NBMAX];              // per-bucket counts
        int lbase[NBMAX];             // global window bases
        int lexc[NBMAX];              // local exclusive prefix
        int cur[NBMAX];               // scatter cursors
        int sorted[256 * EPB];        // bucket-sorted packed edges
    } p;
};

__global__ __launch_bounds__(256) void fused_embed_part_k(
    // gemm args
    const float* __restrict__ xin, const float* __restrict__ embW,
    const float* __restrict__ embB, const float* __restrict__ W,
    const float* __restrict__ asrc, const float* __restrict__ adst,
    __half* __restrict__ hout, float* __restrict__ alpha_s,
    float* __restrict__ alpha_d, int N,
    // partition args
    const int* __restrict__ ei, int* __restrict__ bcnt,
    int* __restrict__ bpack, int E, int PB, int TOT) {
    __shared__ FusedSM sm;
    const int t = threadIdx.x;
    const int bid = blockIdx.x;
    const int p_before = (int)(((long long)bid * PB) / TOT);
    const int p_after  = (int)(((long long)(bid + 1) * PB) / TOT);
    const bool is_part = p_after > p_before;

    if (is_part) {
        // ================= partition role =================
        const int pbid = p_before;
        int dst[EPB], src[EPB];
        int jb = pbid * (256 * EPB) + t;
#pragma unroll
        for (int u = 0; u < EPB; u++) {
            int j = jb + u * 256;
            if (j < E) {
                dst[u] = __builtin_nontemporal_load(&ei[E + j]);
                src[u] = __builtin_nontemporal_load(&ei[j]);
            } else dst[u] = -1;
        }
        sm.p.lcnt[t] = 0; sm.p.lcnt[t + 256] = 0;
        __syncthreads();
#pragma unroll
        for (int u = 0; u < EPB; u++)
            if (dst[u] >= 0) atomicAdd(&sm.p.lcnt[dst[u] >> BSH], 1);
        __syncthreads();
        sm.p.lexc[t] = sm.p.lcnt[t];
        sm.p.lexc[t + 256] = sm.p.lcnt[t + 256];
        __syncthreads();
        int c0 = sm.p.lexc[t], c1 = sm.p.lexc[t + 256];
#pragma unroll
        for (int o = 1; o < NBMAX; o <<= 1) {
            int a0 = (t >= o) ? sm.p.lexc[t - o] : 0;
            int a1 = (t + 256 >= o) ? sm.p.lexc[t + 256 - o] : 0;
            __syncthreads();
            sm.p.lexc[t] += a0;
            sm.p.lexc[t + 256] += a1;
            __syncthreads();
        }
        int e0 = sm.p.lexc[t] - c0, e1 = sm.p.lexc[t + 256] - c1;
        __syncthreads();
        sm.p.lexc[t] = e0; sm.p.lexc[t + 256] = e1;
        sm.p.cur[t] = e0;  sm.p.cur[t + 256] = e1;
        {
            int c = sm.p.lcnt[t];
            sm.p.lbase[t] = c ? t * BCAP + atomicAdd(&bcnt[t], c) : 0;
            c = sm.p.lcnt[t + 256];
            sm.p.lbase[t + 256] = c ? (t + 256) * BCAP + atomicAdd(&bcnt[t + 256], c) : 0;
        }
        __syncthreads();
#pragma unroll
        for (int u = 0; u < EPB; u++) {
            if (dst[u] >= 0) {
                int b = dst[u] >> BSH;
                int pp = atomicAdd(&sm.p.cur[b], 1);
                sm.p.sorted[pp] = (src[u] << BSH) | (dst[u] & (BNODES - 1));
            }
        }
        __syncthreads();
        const int tot = sm.p.lexc[NBMAX - 1] + sm.p.lcnt[NBMAX - 1];
        for (int j = t; j < tot; j += 256) {
            int lo = 0, hi = NBMAX - 1;
            while (lo < hi) {
                int mid = (lo + hi + 1) >> 1;
                if (sm.p.lexc[mid] <= j) lo = mid; else hi = mid - 1;
            }
            bpack[sm.p.lbase[lo] + (j - sm.p.lexc[lo])] = sm.p.sorted[j];
        }
        return;
    }

    // ================= gemm (EMBED) role =================
    const int gidx = bid - p_before;
    const int n0 = gidx * GT;
    if (n0 >= N) return;
    const int rem = N - n0;

#pragma unroll
    for (int j = 0; j < 16; j++) {
        int idx = t + 256 * j;
        int k = idx >> 6, n = idx & 63;
        sm.g.Wt[n * LDH + k] = (_Float16)W[idx];
    }
    for (int j = t; j < GT * NODE_DIM; j += 256)
        sm.g.xe[j] = (j < rem * NODE_DIM) ? xin[(size_t)n0 * NODE_DIM + j] : 0.0f;
    for (int j = t; j < NODE_DIM * HD + HD; j += 256)
        sm.g.we[j] = (j < NODE_DIM * HD) ? embW[j] : embB[j - NODE_DIM * HD];
    __syncthreads();
    {
        int r = t >> 2, d0 = (t & 3) * 16;
#pragma unroll
        for (int jj = 0; jj < 16; jj++) {
            int d = d0 + jj;
            float acc = sm.g.we[NODE_DIM * HD + d];
#pragma unroll
            for (int k = 0; k < NODE_DIM; k++)
                acc = fmaf(sm.g.xe[r * NODE_DIM + k], sm.g.we[k * HD + d], acc);
            sm.g.hs[r * LDH + d] = (r < rem) ? (_Float16)acc : (_Float16)0.0f;
        }
    }
    __syncthreads();

    const int lane = t & 63;
    const int w = t >> 6;
    const int r16 = lane & 15;
    const int g = lane >> 4;

    const _Float16* hrow = sm.g.hs + (w * 16 + r16) * LDH + g * 8;
    f16x8 b0 = *(const f16x8*)(hrow);
    f16x8 b1 = *(const f16x8*)(hrow + 32);

    f32x4 acc[4];
#pragma unroll
    for (int mt = 0; mt < 4; mt++) acc[mt] = (f32x4){0.f, 0.f, 0.f, 0.f};
#pragma unroll
    for (int mt = 0; mt < 4; mt++) {
        const _Float16* arow = sm.g.Wt + (mt * 16 + r16) * LDH + g * 8;
        f16x8 a0 = *(const f16x8*)(arow);
        f16x8 a1 = *(const f16x8*)(arow + 32);
        acc[mt] = __builtin_amdgcn_mfma_f32_16x16x32_f16(a0, b0, acc[mt], 0, 0, 0);
        acc[mt] = __builtin_amdgcn_mfma_f32_16x16x32_f16(a1, b1, acc[mt], 0, 0, 0);
    }

    const int node = n0 + w * 16 + r16;
    float ps = 0.0f, pd = 0.0f;
    if (node < N) {
#pragma unroll
        for (int mt = 0; mt < 4; mt++) {
            float4 av = ((const float4*)asrc)[mt * 4 + g];
            float4 bv = ((const float4*)adst)[mt * 4 + g];
            ps += acc[mt][0] * av.x + acc[mt][1] * av.y +
                  acc[mt][2] * av.z + acc[mt][3] * av.w;
            pd += acc[mt][0] * bv.x + acc[mt][1] * bv.y +
                  acc[mt][2] * bv.z + acc[mt][3] * bv.w;
            short4 s;
            s.x = __half_as_short(__float2half_rn(acc[mt][0]));
            s.y = __half_as_short(__float2half_rn(acc[mt][1]));
            s.z = __half_as_short(__float2half_rn(acc[mt][2]));
            s.w = __half_as_short(__float2half_rn(acc[mt][3]));
            ((short4*)hout)[(size_t)node * 16 + mt * 4 + g] = s;
        }
    }
    ps += __shfl_xor(ps, 16);
    ps += __shfl_xor(ps, 32);
    pd += __shfl_xor(pd, 16);
    pd += __shfl_xor(pd, 32);
    if (g == 0 && node < N) {
        alpha_s[node] = ps;
        alpha_d[node] = pd;
    }
}

// R23: MFMA gemm, layer-2 instance (fp16 h input). Transposed C[dim][node];
// alphas from fp32 acc pre-rounding.
__global__ __launch_bounds__(256) void gemm_alpha_k(
    const __half* __restrict__ hin, const float* __restrict__ W,
    const float* __restrict__ asrc, const float* __restrict__ adst,
    __half* __restrict__ hout, float* __restrict__ alpha_s,
    float* __restrict__ alpha_d, int N) {
    __shared__ _Float16 hs[GT * LDH];
    __shared__ _Float16 Wt[HD * LDH];
    const int t = threadIdx.x;
    const int n0 = blockIdx.x * GT;
    if (n0 >= N) return;
    const int rem = N - n0;

#pragma unroll
    for (int j = 0; j < 16; j++) {
        int idx = t + 256 * j;
        int k = idx >> 6, n = idx & 63;
        Wt[n * LDH + k] = (_Float16)W[idx];
    }
    {
        const short4* g4 = (const short4*)(hin + (size_t)n0 * HD);
#pragma unroll
        for (int j = 0; j < 4; j++) {
            int idx = t + 256 * j;
            int row = idx >> 4, c4 = idx & 15;
            short4 v = {0, 0, 0, 0};
            if (row < rem) v = g4[idx];
            *(short4*)(hs + row * LDH + c4 * 4) = v;
        }
    }
    __syncthreads();

    const int lane = t & 63;
    const int w = t >> 6;
    const int r16 = lane & 15;
    const int g = lane >> 4;

    const _Float16* hrow = hs + (w * 16 + r16) * LDH + g * 8;
    f16x8 b0 = *(const f16x8*)(hrow);
    f16x8 b1 = *(const f16x8*)(hrow + 32);

    f32x4 acc[4];
#pragma unroll
    for (int mt = 0; mt < 4; mt++) acc[mt] = (f32x4){0.f, 0.f, 0.f, 0.f};
#pragma unroll
    for (int mt = 0; mt < 4; mt++) {
        const _Float16* arow = Wt + (mt * 16 + r16) * LDH + g * 8;
        f16x8 a0 = *(const f16x8*)(arow);
        f16x8 a1 = *(const f16x8*)(arow + 32);
        acc[mt] = __builtin_amdgcn_mfma_f32_16x16x32_f16(a0, b0, acc[mt], 0, 0, 0);
        acc[mt] = __builtin_amdgcn_mfma_f32_16x16x32_f16(a1, b1, acc[mt], 0, 0, 0);
    }

    const int node = n0 + w * 16 + r16;
    float ps = 0.0f, pd = 0.0f;
    if (node < N) {
#pragma unroll
        for (int mt = 0; mt < 4; mt++) {
            float4 av = ((const float4*)asrc)[mt * 4 + g];
            float4 bv = ((const float4*)adst)[mt * 4 + g];
            ps += acc[mt][0] * av.x + acc[mt][1] * av.y +
                  acc[mt][2] * av.z + acc[mt][3] * av.w;
            pd += acc[mt][0] * bv.x + acc[mt][1] * bv.y +
                  acc[mt][2] * bv.z + acc[mt][3] * bv.w;
            short4 s;
            s.x = __half_as_short(__float2half_rn(acc[mt][0]));
            s.y = __half_as_short(__float2half_rn(acc[mt][1]));
            s.z = __half_as_short(__float2half_rn(acc[mt][2]));
            s.w = __half_as_short(__float2half_rn(acc[mt][3]));
            ((short4*)hout)[(size_t)node * 16 + mt * 4 + g] = s;
        }
    }
    ps += __shfl_xor(ps, 16);
    ps += __shfl_xor(ps, 32);
    pd += __shfl_xor(pd, 16);
    pd += __shfl_xor(pd, 32);
    if (g == 0 && node < N) {
        alpha_s[node] = ps;
        alpha_d[node] = pd;
    }
}

// block = bucket: inline exclusive scan of bcnt -> e0, then LDS deg
// histogram -> LDS scan -> off -> LDS-cursor scatter of compacted csr_src.
__global__ __launch_bounds__(256) void bucket_csr_k(
    const int* __restrict__ bpack, const int* __restrict__ bcnt,
    int* __restrict__ off, int* __restrict__ csr_src, int N, int NB) {
    __shared__ int s[BNODES];
    __shared__ int lcur[BNODES];
    __shared__ int sred[256];
    const int t = threadIdx.x;
    const int b = blockIdx.x;
    const int nbase = b << BSH;
    const int cnt = bcnt[b];
    const int w0 = b * BCAP;

    int part = 0;
    for (int j = t; j < b; j += 256) part += bcnt[j];
    sred[t] = part;
    s[t] = 0; s[t + 256] = 0;
    __syncthreads();
#pragma unroll
    for (int o = 128; o; o >>= 1) {
        if (t < o) sred[t] += sred[t + o];
        __syncthreads();
    }
    const int e0 = sred[0];

    for (int j = t; j < cnt; j += 256)
        atomicAdd(&s[bpack[w0 + j] & (BNODES - 1)], 1);
    __syncthreads();
    int d0 = s[t], d1 = s[t + 256];
#pragma unroll
    for (int o = 1; o < BNODES; o <<= 1) {
        int a0 = (t >= o) ? s[t - o] : 0;
        int a1 = (t + 256 >= o) ? s[t + 256 - o] : 0;
        __syncthreads();
        s[t] += a0;
        s[t + 256] += a1;
        __syncthreads();
    }
    int ex0 = s[t] - d0, ex1 = s[t + 256] - d1;
    lcur[t] = ex0; lcur[t + 256] = ex1;
    int n0 = nbase + t, n1 = nbase + t + 256;
    if (n0 < N) off[n0] = e0 + ex0;
    if (n1 < N) off[n1] = e0 + ex1;
    if (t == 0 && b == NB - 1) off[N] = e0 + cnt;
    __syncthreads();
    for (int j = t; j < cnt; j += 256) {
        int v = bpack[w0 + j];
        int pos = atomicAdd(&lcur[v & (BNODES - 1)], 1);
        csr_src[e0 + pos] = v >> BSH;
    }
}

// ---------------- fused attention + weighted gather (layer 1) -------------
// wave = 4 consecutive nodes; 16 lanes/node; lane = 4 dims fp16.
// R26: single predicated 8-wide edge loop (clamped idx, masked weight).
template <bool BR>
__global__ __launch_bounds__(256) void gather_k(
    const int* __restrict__ off, const int* __restrict__ csr_src,
    const float* __restrict__ as, const float* __restrict__ ad,
    const __half* __restrict__ h, const float* __restrict__ bias,
    __half* __restrict__ out, int N) {
    int tid = blockIdx.x * blockDim.x + threadIdx.x;
    int wv = tid >> 6;
    int lane = threadIdx.x & 63;
    int grp = lane >> 4;
    int l16 = lane & 15;
    int n = wv * 4 + grp;
    if (n >= N) return;
    int s0 = off[n], s1 = off[n + 1];
    float adv = ad[n];
    const short4* h4 = (const short4*)h;

    float e = as[n] + adv;
    e = (e >= 0.0f) ? e : NEG_SLOPE * e;
    float wsl = __expf(e);
    float l0 = wsl, l1 = 0.0f;
    short4 hvs = h4[(unsigned)(n * 16 + l16)];
    float4 acc0, acc1 = {0, 0, 0, 0};
    acc0.x = wsl * __half2float(__short_as_half(hvs.x));
    acc0.y = wsl * __half2float(__short_as_half(hvs.y));
    acc0.z = wsl * __half2float(__short_as_half(hvs.z));
    acc0.w = wsl * __half2float(__short_as_half(hvs.w));

    const int last = s1 - 1;
    for (int i = s0; i < s1; i += 8) {
        int src[8];
        short4 hv[8];
        float wt[8];
#pragma unroll
        for (int u = 0; u < 8; u++) {
            int idx = i + u;
            src[u] = csr_src[idx < s1 ? idx : last];
        }
#pragma unroll
        for (int u = 0; u < 8; u++)
            hv[u] = h4[(unsigned)(src[u] * 16 + l16)];
#pragma unroll
        for (int u = 0; u < 8; u++) {
            float e0 = as[src[u]] + adv;
            e0 = (e0 >= 0.0f) ? e0 : NEG_SLOPE * e0;
            float w0 = __expf(e0);
            wt[u] = (i + u < s1) ? w0 : 0.0f;
        }
#pragma unroll
        for (int u = 0; u < 8; u += 2) {
            l0 += wt[u];
            l1 += wt[u + 1];
            acc0.x = fmaf(wt[u], __half2float(__short_as_half(hv[u].x)), acc0.x);
            acc0.y = fmaf(wt[u], __half2float(__short_as_half(hv[u].y)), acc0.y);
            acc0.z = fmaf(wt[u], __half2float(__short_as_half(hv[u].z)), acc0.z);
            acc0.w = fmaf(wt[u], __half2float(__short_as_half(hv[u].w)), acc0.w);
            acc1.x = fmaf(wt[u + 1], __half2float(__short_as_half(hv[u + 1].x)), acc1.x);
            acc1.y = fmaf(wt[u + 1], __half2float(__short_as_half(hv[u + 1].y)), acc1.y);
            acc1.z = fmaf(wt[u + 1], __half2float(__short_as_half(hv[u + 1].z)), acc1.z);
            acc1.w = fmaf(wt[u + 1], __half2float(__short_as_half(hv[u + 1].w)), acc1.w);
        }
    }
    float inv = 1.0f / (l0 + l1 + 1e-16f);
    float4 r;
    r.x = (acc0.x + acc1.x) * inv;
    r.y = (acc0.y + acc1.y) * inv;
    r.z = (acc0.z + acc1.z) * inv;
    r.w = (acc0.w + acc1.w) * inv;
    if (BR) {
        float4 b = ((const float4*)bias)[l16];
        r.x = fmaxf(r.x + b.x, 0.0f);
        r.y = fmaxf(r.y + b.y, 0.0f);
        r.z = fmaxf(r.z + b.z, 0.0f);
        r.w = fmaxf(r.w + b.w, 0.0f);
    }
    short4 o;
    o.x = __half_as_short(__float2half_rn(r.x));
    o.y = __half_as_short(__float2half_rn(r.y));
    o.z = __half_as_short(__float2half_rn(r.z));
    o.w = __half_as_short(__float2half_rn(r.w));
    ((short4*)out)[(unsigned)(n * 16 + l16)] = o;
}

// R28: fused layer-2 gather + pool + MLP. Block = one graph (batch sorted),
// 512 threads = 8 waves; wave handles 4 nodes/iter, stride 32. The per-node
// gather is identical to gather_k<false>; pooled mean/max accumulate in
// registers -> 32 LDS slots -> 64-thread reduce -> bias -> fc chain (same
// as the old pool_mlp_k). h_final is never written to global.
__global__ __launch_bounds__(512) void gather_pool_mlp_k(
    const int* __restrict__ off, const int* __restrict__ csr_src,
    const float* __restrict__ as, const float* __restrict__ ad,
    const __half* __restrict__ h, const float* __restrict__ hb,
    const int* __restrict__ batch, int N,
    const float* __restrict__ fc1W, const float* __restrict__ fc1b,
    const float* __restrict__ fc2W, const float* __restrict__ fc2b,
    const float* __restrict__ fc3W, const float* __restrict__ fc3b,
    float* __restrict__ out) {
    __shared__ float psum[32][64];
    __shared__ float pmax[32][64];
    __shared__ float lds[192];
    const int g = blockIdx.x;
    const int t = threadIdx.x;
    const int wv = t >> 6;       // 0..7
    const int lane = t & 63;
    const int grp = lane >> 4;   // 0..3
    const int l16 = lane & 15;
    int lo = 0, hi = N;
    while (lo < hi) { int mid = (lo + hi) >> 1; if (batch[mid] < g) lo = mid + 1; else hi = mid; }
    const int start = lo;
    lo = start; hi = N;
    while (lo < hi) { int mid = (lo + hi) >> 1; if (batch[mid] < g + 1) lo = mid + 1; else hi = mid; }
    const int end = lo;
    const short4* h4 = (const short4*)h;

    float4 sum = {0, 0, 0, 0};
    float4 mx = {-INFINITY, -INFINITY, -INFINITY, -INFINITY};

    for (int nb = start + wv * 4; nb < end; nb += 32) {
        const int n = nb + grp;      // group-uniform predicate
        if (n < end) {
            int s0 = off[n], s1 = off[n + 1];
            float adv = ad[n];
            float e = as[n] + adv;
            e = (e >= 0.0f) ? e : NEG_SLOPE * e;
            float wsl = __expf(e);
            float l0 = wsl, l1 = 0.0f;
            short4 hvs = h4[(unsigned)(n * 16 + l16)];
            float4 acc0, acc1 = {0, 0, 0, 0};
            acc0.x = wsl * __half2float(__short_as_half(hvs.x));
            acc0.y = wsl * __half2float(__short_as_half(hvs.y));
            acc0.z = wsl * __half2float(__short_as_half(hvs.z));
            acc0.w = wsl * __half2float(__short_as_half(hvs.w));

            const int last = s1 - 1;
            for (int i = s0; i < s1; i += 8) {
                int src[8];
                short4 hv[8];
                float wt[8];
#pragma unroll
                for (int u = 0; u < 8; u++) {
                    int idx = i + u;
                    src[u] = csr_src[idx < s1 ? idx : last];
                }
#pragma unroll
                for (int u = 0; u < 8; u++)
                    hv[u] = h4[(unsigned)(src[u] * 16 + l16)];
#pragma unroll
                for (int u = 0; u < 8; u++) {
                    float e0 = as[src[u]] + adv;
                    e0 = (e0 >= 0.0f) ? e0 : NEG_SLOPE * e0;
                    float w0 = __expf(e0);
                    wt[u] = (i + u < s1) ? w0 : 0.0f;
                }
#pragma unroll
                for (int u = 0; u < 8; u += 2) {
                    l0 += wt[u];
                    l1 += wt[u + 1];
                    acc0.x = fmaf(wt[u], __half2float(__short_as_half(hv[u].x)), acc0.x);
                    acc0.y = fmaf(wt[u], __half2float(__short_as_half(hv[u].y)), acc0.y);
                    acc0.z = fmaf(wt[u], __half2float(__short_as_half(hv[u].z)), acc0.z);
                    acc0.w = fmaf(wt[u], __half2float(__short_as_half(hv[u].w)), acc0.w);
                    acc1.x = fmaf(wt[u + 1], __half2float(__short_as_half(hv[u + 1].x)), acc1.x);
                    acc1.y = fmaf(wt[u + 1], __half2float(__short_as_half(hv[u + 1].y)), acc1.y);
                    acc1.z = fmaf(wt[u + 1], __half2float(__short_as_half(hv[u + 1].z)), acc1.z);
                    acc1.w = fmaf(wt[u + 1], __half2float(__short_as_half(hv[u + 1].w)), acc1.w);
                }
            }
            float inv = 1.0f / (l0 + l1 + 1e-16f);
            float4 r;
            r.x = (acc0.x + acc1.x) * inv;
            r.y = (acc0.y + acc1.y) * inv;
            r.z = (acc0.z + acc1.z) * inv;
            r.w = (acc0.w + acc1.w) * inv;
            // match old pipeline numerics: h_final was stored as fp16
            r.x = __half2float(__float2half_rn(r.x));
            r.y = __half2float(__float2half_rn(r.y));
            r.z = __half2float(__float2half_rn(r.z));
            r.w = __half2float(__float2half_rn(r.w));
            sum.x += r.x; sum.y += r.y; sum.z += r.z; sum.w += r.w;
            mx.x = fmaxf(mx.x, r.x); mx.y = fmaxf(mx.y, r.y);
            mx.z = fmaxf(mx.z, r.z); mx.w = fmaxf(mx.w, r.w);
        }
    }
    const int slot = wv * 4 + grp;
    *(float4*)&psum[slot][l16 * 4] = sum;
    *(float4*)&pmax[slot][l16 * 4] = mx;
    __syncthreads();
    if (t < 64) {
        float s = 0.0f, m = -INFINITY;
#pragma unroll
        for (int k = 0; k < 32; k++) {
            s += psum[k][t];
            m = fmaxf(m, pmax[k][t]);
        }
        int cnt = end - start;
        float bias = hb[t];
        lds[t]      = (cnt > 0) ? s / (float)cnt + bias : 0.0f;
        lds[64 + t] = (cnt > 0) ? m + bias : 0.0f;
    }
    __syncthreads();
    if (t < 64) {
        int lane2 = t;
        float o1 = fc1b[lane2];
        for (int k = 0; k < 128; k++) o1 += lds[k] * fc1W[k * 64 + lane2];
        o1 = fmaxf(o1, 0.0f);
        __builtin_amdgcn_s_barrier();  // wave-0 internal only; others done
        lds[128 + lane2] = o1;
        float o2 = 0.0f;
        if (lane2 < 32) {
            o2 = fc2b[lane2];
            for (int k = 0; k < 64; k++) o2 += lds[128 + k] * fc2W[k * 32 + lane2];
            o2 = fmaxf(o2, 0.0f);
        }
        float part = (lane2 < 32) ? o2 * fc3W[lane2] : 0.0f;
#pragma unroll
        for (int off2 = 32; off2; off2 >>= 1) part += __shfl_xor(part, off2);
        if (lane2 == 0) out[g] = part + fc3b[0];
    }
}

static inline size_t align256(size_t x) { return (x + 255) & ~(size_t)255; }

extern "C" void kernel_launch(void* const* d_in, const int* in_sizes, int n_in,
                              void* d_out, int out_size, void* d_ws, size_t ws_size,
                              hipStream_t stream) {
    const float* x      = (const float*)d_in[0];
    const int*   ei     = (const int*)d_in[1];
    const int*   batch  = (const int*)d_in[2];
    const float* embW   = (const float*)d_in[3];
    const float* embB   = (const float*)d_in[4];
    const float* g1W    = (const float*)d_in[5];
    const float* g1as   = (const float*)d_in[6];
    const float* g1ad   = (const float*)d_in[7];
    const float* g1b    = (const float*)d_in[8];
    const float* g2W    = (const float*)d_in[9];
    const float* g2as   = (const float*)d_in[10];
    const float* g2ad   = (const float*)d_in[11];
    const float* g2b    = (const float*)d_in[12];
    const float* fc1W   = (const float*)d_in[13];
    const float* fc1b   = (const float*)d_in[14];
    const float* fc2W   = (const float*)d_in[15];
    const float* fc2b   = (const float*)d_in[16];
    const float* fc3W   = (const float*)d_in[17];
    const float* fc3b   = (const float*)d_in[18];
    float* out = (float*)d_out;

    const int N  = in_sizes[0] / NODE_DIM;   // 200000
    const int E  = in_sizes[1] / 2;          // 1200000
    const int G  = out_size;                 // 2048
    const int NH = N * HD;
    const int NB = (N + BNODES - 1) >> BSH;  // 391 buckets

    char* ws = (char*)d_ws;
    __half* bufA    = (__half*)ws; ws += align256((size_t)NH * 2);
    __half* bufB    = (__half*)ws; ws += align256((size_t)NH * 2);
    float*  as_buf  = (float*)ws;  ws += align256((size_t)N * 4);
    float*  ad_buf  = (float*)ws;  ws += align256((size_t)N * 4);
    int*    off     = (int*)ws;    ws += align256((size_t)(N + 1) * 4);
    int*    bcnt    = (int*)ws;    ws += align256((size_t)NBMAX * 4);
    int*    bpack   = (int*)ws;    ws += align256((size_t)NB * BCAP * 4);
    int*    csrsrc  = (int*)ws;    ws += align256((size_t)E * 4);

    const int B = 256;
    dim3 blk(B);
    const int GB = (N + GT - 1) / GT;               // 3125 gemm blocks
    const int PB = (E + B * EPB - 1) / (B * EPB);   // 586 partition blocks
    const int TOT = GB + PB;
    dim3 gr_gath(((N + 3) / 4 * 64 + B - 1) / B);   // wave-per-4-nodes

    // bcnt must be zero before any partition block's reservation
    zero_k<<<dim3(2), blk, 0, stream>>>(bcnt, NBMAX);
    // gemm1 (embed fused) || edge partition, interleaved roles
    fused_embed_part_k<<<dim3(TOT), blk, 0, stream>>>(
        x, embW, embB, g1W, g1as, g1ad, bufB, as_buf, ad_buf, N,
        ei, bcnt, bpack, E, PB, TOT);
    bucket_csr_k<<<dim3(NB), blk, 0, stream>>>(bpack, bcnt, off, csrsrc, N, NB);

    // ======== GAT layer 1 gather ========
    gather_k<true><<<gr_gath, blk, 0, stream>>>(off, csrsrc, as_buf, ad_buf,
                                                bufB, g1b, bufA, N);

    // ======== GAT layer 2 gemm ========
    gemm_alpha_k<<<dim3(GB), blk, 0, stream>>>(bufA, g2W, g2as, g2ad,
                                               bufB, as_buf, ad_buf, N);

    // ======== layer-2 gather + pool + MLP fused (per-graph blocks) ========
    gather_pool_mlp_k<<<dim3(G), dim3(512), 0, stream>>>(
        off, csrsrc, as_buf, ad_buf, bufB, g2b, batch, N,
        fc1W, fc1b, fc2W, fc2b, fc3W, fc3b, out);
}

// Round 7
// 254.240 us; speedup vs baseline: 1.0553x; 1.0553x over previous
//
#include <hip/hip_runtime.h>
#include <hip/hip_bf16.h>
#include <hip/hip_fp16.h>

#define HD 64
#define NODE_DIM 5
#define NEG_SLOPE 0.2f
#define GT 64       // gemm node-tile per block
#define BSH 9       // bucket shift: 512 nodes/bucket
#define BNODES 512  // nodes per bucket
#define NBMAX 512   // static bucket array cap (N<=262144)
#define BCAP 4096   // fixed bucket window capacity (mean 3072, sigma 55 -> 18 sigma slack)
#define EPB 8       // edges per thread in bucket kernels
#define LDH 72      // LDS row stride in halves: 144B = 16B-aligned, bank-stride 4 -> only free 2-way aliasing

typedef _Float16 f16x8 __attribute__((ext_vector_type(8)));
typedef float f32x4 __attribute__((ext_vector_type(4)));

// R27: gemm1 || partition fused (Bresenham roles, union'd LDS, LDS bucket
// sort -> coalesced window runs). R28 (REVERTED R29): per-graph gather+pool
// fusion starved the gather of TLP (74us @ 15% HBM) — random-gather speed
// comes purely from wave count; keep 50K-wave gather kernels.
// R29: prep_k pre-converts W -> fp16 WtT (kills 16 scalar loads/thread of
// staging in 6250 gemm blocks; Wt LDS gone -> occupancy up) and precomputes
// graph boundaries gstart[] (kills pool's 2 dependent binsearches).

// prep: zero bcnt + W->fp16 transposed + graph boundaries from sorted batch
__global__ __launch_bounds__(256) void prep_k(
    int* __restrict__ bcnt, const float* __restrict__ g1W,
    const float* __restrict__ g2W, __half* __restrict__ wt1,
    __half* __restrict__ wt2, const int* __restrict__ batch,
    int* __restrict__ gstart, int N, int G) {
    int i = blockIdx.x * 256 + threadIdx.x;
    if (i < NBMAX) bcnt[i] = 0;
    if (i < HD * HD) {
        int k = i >> 6, n = i & 63;          // W[k][n] row-major
        wt1[n * HD + k] = __float2half_rn(g1W[i]);  // WtT[n][k]
        wt2[n * HD + k] = __float2half_rn(g2W[i]);
    }
    if (i < N) {
        int b = batch[i];
        int bn = (i + 1 < N) ? batch[i + 1] : G;
        if (i == 0)
            for (int g = 0; g <= b; g++) gstart[g] = 0;
        for (int g = b + 1; g <= bn; g++) gstart[g] = i + 1;
    }
}

union FusedSM {
    struct {
        _Float16 hs[GT * LDH];        // h tile  [node][k]
        float xe[GT * NODE_DIM];
        float we[NODE_DIM * HD + HD];
    } g;
    struct {
        int lcnt[NBMAX];              // per-bucket counts
        int lbase[NBMAX];             // global window bases
        int lexc[NBMAX];              // local exclusive prefix
        int cur[NBMAX];               // scatter cursors
        int sorted[256 * EPB];        // bucket-sorted packed edges
    } p;
};

__global__ __launch_bounds__(256) void fused_embed_part_k(
    // gemm args
    const float* __restrict__ xin, const float* __restrict__ embW,
    const float* __restrict__ embB, const __half* __restrict__ wtT,
    const float* __restrict__ asrc, const float* __restrict__ adst,
    __half* __restrict__ hout, float* __restrict__ alpha_s,
    float* __restrict__ alpha_d, int N,
    // partition args
    const int* __restrict__ ei, int* __restrict__ bcnt,
    int* __restrict__ bpack, int E, int PB, int TOT) {
    __shared__ FusedSM sm;
    const int t = threadIdx.x;
    const int bid = blockIdx.x;
    const int p_before = (int)(((long long)bid * PB) / TOT);
    const int p_after  = (int)(((long long)(bid + 1) * PB) / TOT);
    const bool is_part = p_after > p_before;

    if (is_part) {
        // ================= partition role =================
        const int pbid = p_before;
        int dst[EPB], src[EPB];
        int jb = pbid * (256 * EPB) + t;
#pragma unroll
        for (int u = 0; u < EPB; u++) {
            int j = jb + u * 256;
            if (j < E) {
                dst[u] = __builtin_nontemporal_load(&ei[E + j]);
                src[u] = __builtin_nontemporal_load(&ei[j]);
            } else dst[u] = -1;
        }
        sm.p.lcnt[t] = 0; sm.p.lcnt[t + 256] = 0;
        __syncthreads();
#pragma unroll
        for (int u = 0; u < EPB; u++)
            if (dst[u] >= 0) atomicAdd(&sm.p.lcnt[dst[u] >> BSH], 1);
        __syncthreads();
        sm.p.lexc[t] = sm.p.lcnt[t];
        sm.p.lexc[t + 256] = sm.p.lcnt[t + 256];
        __syncthreads();
        int c0 = sm.p.lexc[t], c1 = sm.p.lexc[t + 256];
#pragma unroll
        for (int o = 1; o < NBMAX; o <<= 1) {
            int a0 = (t >= o) ? sm.p.lexc[t - o] : 0;
            int a1 = (t + 256 >= o) ? sm.p.lexc[t + 256 - o] : 0;
            __syncthreads();
            sm.p.lexc[t] += a0;
            sm.p.lexc[t + 256] += a1;
            __syncthreads();
        }
        int e0 = sm.p.lexc[t] - c0, e1 = sm.p.lexc[t + 256] - c1;
        __syncthreads();
        sm.p.lexc[t] = e0; sm.p.lexc[t + 256] = e1;
        sm.p.cur[t] = e0;  sm.p.cur[t + 256] = e1;
        {
            int c = sm.p.lcnt[t];
            sm.p.lbase[t] = c ? t * BCAP + atomicAdd(&bcnt[t], c) : 0;
            c = sm.p.lcnt[t + 256];
            sm.p.lbase[t + 256] = c ? (t + 256) * BCAP + atomicAdd(&bcnt[t + 256], c) : 0;
        }
        __syncthreads();
#pragma unroll
        for (int u = 0; u < EPB; u++) {
            if (dst[u] >= 0) {
                int b = dst[u] >> BSH;
                int pp = atomicAdd(&sm.p.cur[b], 1);
                sm.p.sorted[pp] = (src[u] << BSH) | (dst[u] & (BNODES - 1));
            }
        }
        __syncthreads();
        const int tot = sm.p.lexc[NBMAX - 1] + sm.p.lcnt[NBMAX - 1];
        for (int j = t; j < tot; j += 256) {
            int lo = 0, hi = NBMAX - 1;
            while (lo < hi) {
                int mid = (lo + hi + 1) >> 1;
                if (sm.p.lexc[mid] <= j) lo = mid; else hi = mid - 1;
            }
            bpack[sm.p.lbase[lo] + (j - sm.p.lexc[lo])] = sm.p.sorted[j];
        }
        return;
    }

    // ================= gemm (EMBED) role =================
    const int gidx = bid - p_before;
    const int n0 = gidx * GT;
    if (n0 >= N) return;
    const int rem = N - n0;

    for (int j = t; j < GT * NODE_DIM; j += 256)
        sm.g.xe[j] = (j < rem * NODE_DIM) ? xin[(size_t)n0 * NODE_DIM + j] : 0.0f;
    for (int j = t; j < NODE_DIM * HD + HD; j += 256)
        sm.g.we[j] = (j < NODE_DIM * HD) ? embW[j] : embB[j - NODE_DIM * HD];
    __syncthreads();
    {
        int r = t >> 2, d0 = (t & 3) * 16;
#pragma unroll
        for (int jj = 0; jj < 16; jj++) {
            int d = d0 + jj;
            float acc = sm.g.we[NODE_DIM * HD + d];
#pragma unroll
            for (int k = 0; k < NODE_DIM; k++)
                acc = fmaf(sm.g.xe[r * NODE_DIM + k], sm.g.we[k * HD + d], acc);
            sm.g.hs[r * LDH + d] = (r < rem) ? (_Float16)acc : (_Float16)0.0f;
        }
    }
    __syncthreads();

    const int lane = t & 63;
    const int w = t >> 6;
    const int r16 = lane & 15;
    const int g = lane >> 4;

    const _Float16* hrow = sm.g.hs + (w * 16 + r16) * LDH + g * 8;
    f16x8 b0 = *(const f16x8*)(hrow);
    f16x8 b1 = *(const f16x8*)(hrow + 32);

    f32x4 acc[4];
#pragma unroll
    for (int mt = 0; mt < 4; mt++) acc[mt] = (f32x4){0.f, 0.f, 0.f, 0.f};
#pragma unroll
    for (int mt = 0; mt < 4; mt++) {
        const _Float16* arow = (const _Float16*)wtT + (mt * 16 + r16) * HD + g * 8;
        f16x8 a0 = *(const f16x8*)(arow);
        f16x8 a1 = *(const f16x8*)(arow + 32);
        acc[mt] = __builtin_amdgcn_mfma_f32_16x16x32_f16(a0, b0, acc[mt], 0, 0, 0);
        acc[mt] = __builtin_amdgcn_mfma_f32_16x16x32_f16(a1, b1, acc[mt], 0, 0, 0);
    }

    const int node = n0 + w * 16 + r16;
    float ps = 0.0f, pd = 0.0f;
    if (node < N) {
#pragma unroll
        for (int mt = 0; mt < 4; mt++) {
            float4 av = ((const float4*)asrc)[mt * 4 + g];
            float4 bv = ((const float4*)adst)[mt * 4 + g];
            ps += acc[mt][0] * av.x + acc[mt][1] * av.y +
                  acc[mt][2] * av.z + acc[mt][3] * av.w;
            pd += acc[mt][0] * bv.x + acc[mt][1] * bv.y +
                  acc[mt][2] * bv.z + acc[mt][3] * bv.w;
            short4 s;
            s.x = __half_as_short(__float2half_rn(acc[mt][0]));
            s.y = __half_as_short(__float2half_rn(acc[mt][1]));
            s.z = __half_as_short(__float2half_rn(acc[mt][2]));
            s.w = __half_as_short(__float2half_rn(acc[mt][3]));
            ((short4*)hout)[(size_t)node * 16 + mt * 4 + g] = s;
        }
    }
    ps += __shfl_xor(ps, 16);
    ps += __shfl_xor(ps, 32);
    pd += __shfl_xor(pd, 16);
    pd += __shfl_xor(pd, 32);
    if (g == 0 && node < N) {
        alpha_s[node] = ps;
        alpha_d[node] = pd;
    }
}

// R23/R29: MFMA gemm, layer-2 instance. h tile in LDS; W fragments straight
// from pre-transposed fp16 WtT in global (L1/L2-hot 8KB). Transposed
// C[dim][node]; alphas from fp32 acc pre-rounding.
__global__ __launch_bounds__(256) void gemm_alpha_k(
    const __half* __restrict__ hin, const __half* __restrict__ wtT,
    const float* __restrict__ asrc, const float* __restrict__ adst,
    __half* __restrict__ hout, float* __restrict__ alpha_s,
    float* __restrict__ alpha_d, int N) {
    __shared__ _Float16 hs[GT * LDH];
    const int t = threadIdx.x;
    const int n0 = blockIdx.x * GT;
    if (n0 >= N) return;
    const int rem = N - n0;

    {
        const short4* g4 = (const short4*)(hin + (size_t)n0 * HD);
#pragma unroll
        for (int j = 0; j < 4; j++) {
            int idx = t + 256 * j;
            int row = idx >> 4, c4 = idx & 15;
            short4 v = {0, 0, 0, 0};
            if (row < rem) v = g4[idx];
            *(short4*)(hs + row * LDH + c4 * 4) = v;
        }
    }
    __syncthreads();

    const int lane = t & 63;
    const int w = t >> 6;
    const int r16 = lane & 15;
    const int g = lane >> 4;

    const _Float16* hrow = hs + (w * 16 + r16) * LDH + g * 8;
    f16x8 b0 = *(const f16x8*)(hrow);
    f16x8 b1 = *(const f16x8*)(hrow + 32);

    f32x4 acc[4];
#pragma unroll
    for (int mt = 0; mt < 4; mt++) acc[mt] = (f32x4){0.f, 0.f, 0.f, 0.f};
#pragma unroll
    for (int mt = 0; mt < 4; mt++) {
        const _Float16* arow = (const _Float16*)wtT + (mt * 16 + r16) * HD + g * 8;
        f16x8 a0 = *(const f16x8*)(arow);
        f16x8 a1 = *(const f16x8*)(arow + 32);
        acc[mt] = __builtin_amdgcn_mfma_f32_16x16x32_f16(a0, b0, acc[mt], 0, 0, 0);
        acc[mt] = __builtin_amdgcn_mfma_f32_16x16x32_f16(a1, b1, acc[mt], 0, 0, 0);
    }

    const int node = n0 + w * 16 + r16;
    float ps = 0.0f, pd = 0.0f;
    if (node < N) {
#pragma unroll
        for (int mt = 0; mt < 4; mt++) {
            float4 av = ((const float4*)asrc)[mt * 4 + g];
            float4 bv = ((const float4*)adst)[mt * 4 + g];
            ps += acc[mt][0] * av.x + acc[mt][1] * av.y +
                  acc[mt][2] * av.z + acc[mt][3] * av.w;
            pd += acc[mt][0] * bv.x + acc[mt][1] * bv.y +
                  acc[mt][2] * bv.z + acc[mt][3] * bv.w;
            short4 s;
            s.x = __half_as_short(__float2half_rn(acc[mt][0]));
            s.y = __half_as_short(__float2half_rn(acc[mt][1]));
            s.z = __half_as_short(__float2half_rn(acc[mt][2]));
            s.w = __half_as_short(__float2half_rn(acc[mt][3]));
            ((short4*)hout)[(size_t)node * 16 + mt * 4 + g] = s;
        }
    }
    ps += __shfl_xor(ps, 16);
    ps += __shfl_xor(ps, 32);
    pd += __shfl_xor(pd, 16);
    pd += __shfl_xor(pd, 32);
    if (g == 0 && node < N) {
        alpha_s[node] = ps;
        alpha_d[node] = pd;
    }
}

// block = bucket: inline exclusive scan of bcnt -> e0, then LDS deg
// histogram -> LDS scan -> off -> LDS-cursor scatter of compacted csr_src.
__global__ __launch_bounds__(256) void bucket_csr_k(
    const int* __restrict__ bpack, const int* __restrict__ bcnt,
    int* __restrict__ off, int* __restrict__ csr_src, int N, int NB) {
    __shared__ int s[BNODES];
    __shared__ int lcur[BNODES];
    __shared__ int sred[256];
    const int t = threadIdx.x;
    const int b = blockIdx.x;
    const int nbase = b << BSH;
    const int cnt = bcnt[b];
    const int w0 = b * BCAP;

    int part = 0;
    for (int j = t; j < b; j += 256) part += bcnt[j];
    sred[t] = part;
    s[t] = 0; s[t + 256] = 0;
    __syncthreads();
#pragma unroll
    for (int o = 128; o; o >>= 1) {
        if (t < o) sred[t] += sred[t + o];
        __syncthreads();
    }
    const int e0 = sred[0];

    for (int j = t; j < cnt; j += 256)
        atomicAdd(&s[bpack[w0 + j] & (BNODES - 1)], 1);
    __syncthreads();
    int d0 = s[t], d1 = s[t + 256];
#pragma unroll
    for (int o = 1; o < BNODES; o <<= 1) {
        int a0 = (t >= o) ? s[t - o] : 0;
        int a1 = (t + 256 >= o) ? s[t + 256 - o] : 0;
        __syncthreads();
        s[t] += a0;
        s[t + 256] += a1;
        __syncthreads();
    }
    int ex0 = s[t] - d0, ex1 = s[t + 256] - d1;
    lcur[t] = ex0; lcur[t + 256] = ex1;
    int n0 = nbase + t, n1 = nbase + t + 256;
    if (n0 < N) off[n0] = e0 + ex0;
    if (n1 < N) off[n1] = e0 + ex1;
    if (t == 0 && b == NB - 1) off[N] = e0 + cnt;
    __syncthreads();
    for (int j = t; j < cnt; j += 256) {
        int v = bpack[w0 + j];
        int pos = atomicAdd(&lcur[v & (BNODES - 1)], 1);
        csr_src[e0 + pos] = v >> BSH;
    }
}

// ---------------- fused attention + weighted gather -----------------------
// wave = 4 consecutive nodes; 16 lanes/node; lane = 4 dims fp16.
// R26: single predicated 8-wide edge loop (clamped idx, masked weight).
// Max-TLP form (R29 lesson): one node-quad per wave, never serialize.
template <bool BR>
__global__ __launch_bounds__(256) void gather_k(
    const int* __restrict__ off, const int* __restrict__ csr_src,
    const float* __restrict__ as, const float* __restrict__ ad,
    const __half* __restrict__ h, const float* __restrict__ bias,
    __half* __restrict__ out, int N) {
    int tid = blockIdx.x * blockDim.x + threadIdx.x;
    int wv = tid >> 6;
    int lane = threadIdx.x & 63;
    int grp = lane >> 4;
    int l16 = lane & 15;
    int n = wv * 4 + grp;
    if (n >= N) return;
    int s0 = off[n], s1 = off[n + 1];
    float adv = ad[n];
    const short4* h4 = (const short4*)h;

    float e = as[n] + adv;
    e = (e >= 0.0f) ? e : NEG_SLOPE * e;
    float wsl = __expf(e);
    float l0 = wsl, l1 = 0.0f;
    short4 hvs = h4[(unsigned)(n * 16 + l16)];
    float4 acc0, acc1 = {0, 0, 0, 0};
    acc0.x = wsl * __half2float(__short_as_half(hvs.x));
    acc0.y = wsl * __half2float(__short_as_half(hvs.y));
    acc0.z = wsl * __half2float(__short_as_half(hvs.z));
    acc0.w = wsl * __half2float(__short_as_half(hvs.w));

    const int last = s1 - 1;
    for (int i = s0; i < s1; i += 8) {
        int src[8];
        short4 hv[8];
        float wt[8];
#pragma unroll
        for (int u = 0; u < 8; u++) {
            int idx = i + u;
            src[u] = csr_src[idx < s1 ? idx : last];
        }
#pragma unroll
        for (int u = 0; u < 8; u++)
            hv[u] = h4[(unsigned)(src[u] * 16 + l16)];
#pragma unroll
        for (int u = 0; u < 8; u++) {
            float e0 = as[src[u]] + adv;
            e0 = (e0 >= 0.0f) ? e0 : NEG_SLOPE * e0;
            float w0 = __expf(e0);
            wt[u] = (i + u < s1) ? w0 : 0.0f;
        }
#pragma unroll
        for (int u = 0; u < 8; u += 2) {
            l0 += wt[u];
            l1 += wt[u + 1];
            acc0.x = fmaf(wt[u], __half2float(__short_as_half(hv[u].x)), acc0.x);
            acc0.y = fmaf(wt[u], __half2float(__short_as_half(hv[u].y)), acc0.y);
            acc0.z = fmaf(wt[u], __half2float(__short_as_half(hv[u].z)), acc0.z);
            acc0.w = fmaf(wt[u], __half2float(__short_as_half(hv[u].w)), acc0.w);
            acc1.x = fmaf(wt[u + 1], __half2float(__short_as_half(hv[u + 1].x)), acc1.x);
            acc1.y = fmaf(wt[u + 1], __half2float(__short_as_half(hv[u + 1].y)), acc1.y);
            acc1.z = fmaf(wt[u + 1], __half2float(__short_as_half(hv[u + 1].z)), acc1.z);
            acc1.w = fmaf(wt[u + 1], __half2float(__short_as_half(hv[u + 1].w)), acc1.w);
        }
    }
    float inv = 1.0f / (l0 + l1 + 1e-16f);
    float4 r;
    r.x = (acc0.x + acc1.x) * inv;
    r.y = (acc0.y + acc1.y) * inv;
    r.z = (acc0.z + acc1.z) * inv;
    r.w = (acc0.w + acc1.w) * inv;
    if (BR) {
        float4 b = ((const float4*)bias)[l16];
        r.x = fmaxf(r.x + b.x, 0.0f);
        r.y = fmaxf(r.y + b.y, 0.0f);
        r.z = fmaxf(r.z + b.z, 0.0f);
        r.w = fmaxf(r.w + b.w, 0.0f);
    }
    short4 o;
    o.x = __half_as_short(__float2half_rn(r.x));
    o.y = __half_as_short(__float2half_rn(r.y));
    o.z = __half_as_short(__float2half_rn(r.z));
    o.w = __half_as_short(__float2half_rn(r.w));
    ((short4*)out)[(unsigned)(n * 16 + l16)] = o;
}

// R24: vectorized pool — 16 lanes/node, short4 (8B) loads; bias applied
// AFTER pooling (const per dim). R29: graph bounds from precomputed gstart
// (binsearches removed). fc chain: wave-0 pattern.
__global__ __launch_bounds__(256) void pool_mlp_k(
    const __half* __restrict__ hfin, const float* __restrict__ hb,
    const int* __restrict__ gstart, int N,
    const float* __restrict__ fc1W, const float* __restrict__ fc1b,
    const float* __restrict__ fc2W, const float* __restrict__ fc2b,
    const float* __restrict__ fc3W, const float* __restrict__ fc3b,
    float* __restrict__ out) {
    __shared__ float psum[16][64];
    __shared__ float pmax[16][64];
    __shared__ float lds[192];
    int g = blockIdx.x;
    int t = threadIdx.x;
    int gg = t >> 4;
    int l16 = t & 15;
    int start = gstart[g];
    int end = gstart[g + 1];
    const short4* h4 = (const short4*)hfin;
    float4 sum = {0, 0, 0, 0};
    float4 mx = {-INFINITY, -INFINITY, -INFINITY, -INFINITY};
    for (int n = start + gg; n < end; n += 16) {
        short4 v = h4[(size_t)n * 16 + l16];
        float a = __half2float(__short_as_half(v.x));
        float b = __half2float(__short_as_half(v.y));
        float c = __half2float(__short_as_half(v.z));
        float d = __half2float(__short_as_half(v.w));
        sum.x += a; sum.y += b; sum.z += c; sum.w += d;
        mx.x = fmaxf(mx.x, a); mx.y = fmaxf(mx.y, b);
        mx.z = fmaxf(mx.z, c); mx.w = fmaxf(mx.w, d);
    }
    *(float4*)&psum[gg][l16 * 4] = sum;
    *(float4*)&pmax[gg][l16 * 4] = mx;
    __syncthreads();
    if (t < 64) {
        float s = 0.0f, m = -INFINITY;
#pragma unroll
        for (int k = 0; k < 16; k++) {
            s += psum[k][t];
            m = fmaxf(m, pmax[k][t]);
        }
        int cnt = end - start;
        float bias = hb[t];
        lds[t]      = (cnt > 0) ? s / (float)cnt + bias : 0.0f;
        lds[64 + t] = (cnt > 0) ? m + bias : 0.0f;
    }
    __syncthreads();
    if (t < 64) {
        int lane = t;
        float o1 = fc1b[lane];
        for (int k = 0; k < 128; k++) o1 += lds[k] * fc1W[k * 64 + lane];
        o1 = fmaxf(o1, 0.0f);
        __builtin_amdgcn_s_barrier();  // wave-0 internal only; others done
        lds[128 + lane] = o1;
        float o2 = 0.0f;
        if (lane < 32) {
            o2 = fc2b[lane];
            for (int k = 0; k < 64; k++) o2 += lds[128 + k] * fc2W[k * 32 + lane];
            o2 = fmaxf(o2, 0.0f);
        }
        float part = (lane < 32) ? o2 * fc3W[lane] : 0.0f;
#pragma unroll
        for (int off = 32; off; off >>= 1) part += __shfl_xor(part, off);
        if (lane == 0) out[g] = part + fc3b[0];
    }
}

static inline size_t align256(size_t x) { return (x + 255) & ~(size_t)255; }

extern "C" void kernel_launch(void* const* d_in, const int* in_sizes, int n_in,
                              void* d_out, int out_size, void* d_ws, size_t ws_size,
                              hipStream_t stream) {
    const float* x      = (const float*)d_in[0];
    const int*   ei     = (const int*)d_in[1];
    const int*   batch  = (const int*)d_in[2];
    const float* embW   = (const float*)d_in[3];
    const float* embB   = (const float*)d_in[4];
    const float* g1W    = (const float*)d_in[5];
    const float* g1as   = (const float*)d_in[6];
    const float* g1ad   = (const float*)d_in[7];
    const float* g1b    = (const float*)d_in[8];
    const float* g2W    = (const float*)d_in[9];
    const float* g2as   = (const float*)d_in[10];
    const float* g2ad   = (const float*)d_in[11];
    const float* g2b    = (const float*)d_in[12];
    const float* fc1W   = (const float*)d_in[13];
    const float* fc1b   = (const float*)d_in[14];
    const float* fc2W   = (const float*)d_in[15];
    const float* fc2b   = (const float*)d_in[16];
    const float* fc3W   = (const float*)d_in[17];
    const float* fc3b   = (const float*)d_in[18];
    float* out = (float*)d_out;

    const int N  = in_sizes[0] / NODE_DIM;   // 200000
    const int E  = in_sizes[1] / 2;          // 1200000
    const int G  = out_size;                 // 2048
    const int NH = N * HD;
    const int NB = (N + BNODES - 1) >> BSH;  // 391 buckets

    char* ws = (char*)d_ws;
    __half* bufA    = (__half*)ws; ws += align256((size_t)NH * 2);
    __half* bufB    = (__half*)ws; ws += align256((size_t)NH * 2);
    float*  as_buf  = (float*)ws;  ws += align256((size_t)N * 4);
    float*  ad_buf  = (float*)ws;  ws += align256((size_t)N * 4);
    int*    off     = (int*)ws;    ws += align256((size_t)(N + 1) * 4);
    int*    bcnt    = (int*)ws;    ws += align256((size_t)NBMAX * 4);
    __half* wt1     = (__half*)ws; ws += align256((size_t)HD * HD * 2);
    __half* wt2     = (__half*)ws; ws += align256((size_t)HD * HD * 2);
    int*    gstart  = (int*)ws;    ws += align256((size_t)(G + 1) * 4);
    int*    bpack   = (int*)ws;    ws += align256((size_t)NB * BCAP * 4);
    int*    csrsrc  = (int*)ws;    ws += align256((size_t)E * 4);

    const int B = 256;
    dim3 blk(B);
    const int GB = (N + GT - 1) / GT;               // 3125 gemm blocks
    const int PB = (E + B * EPB - 1) / (B * EPB);   // 586 partition blocks
    const int TOT = GB + PB;
    dim3 gr_gath(((N + 3) / 4 * 64 + B - 1) / B);   // wave-per-4-nodes

    // prep: zero bcnt + fp16 WtT conversion + graph boundaries
    prep_k<<<dim3((N + B - 1) / B), blk, 0, stream>>>(bcnt, g1W, g2W, wt1, wt2,
                                                      batch, gstart, N, G);
    // gemm1 (embed fused) || edge partition, interleaved roles
    fused_embed_part_k<<<dim3(TOT), blk, 0, stream>>>(
        x, embW, embB, wt1, g1as, g1ad, bufB, as_buf, ad_buf, N,
        ei, bcnt, bpack, E, PB, TOT);
    bucket_csr_k<<<dim3(NB), blk, 0, stream>>>(bpack, bcnt, off, csrsrc, N, NB);

    // ======== GAT layer 1 gather ========
    gather_k<true><<<gr_gath, blk, 0, stream>>>(off, csrsrc, as_buf, ad_buf,
                                                bufB, g1b, bufA, N);

    // ======== GAT layer 2 gemm ========
    gemm_alpha_k<<<dim3(GB), blk, 0, stream>>>(bufA, wt2, g2as, g2ad,
                                               bufB, as_buf, ad_buf, N);
    gather_k<false><<<gr_gath, blk, 0, stream>>>(off, csrsrc, as_buf, ad_buf,
                                                 bufB, nullptr, bufA, N);

    // ---- pooling + MLP (g2 bias applied here)
    pool_mlp_k<<<dim3(G), dim3(256), 0, stream>>>(bufA, g2b, gstart, N,
                                                  fc1W, fc1b, fc2W, fc2b, fc3W, fc3b, out);
}